// Round 6
// baseline (1289.535 us; speedup 1.0000x reference)
//
#include <hip/hip_runtime.h>
#include <math.h>

#define SEQ   1024
#define BATCH 1024
#define IN_F  57
#define H_F   128
#define OUT_F 18
#define MROWS 16     // batch rows per block
#define HSTR  136    // h_lds row stride in bf16 (272 B, 16B-aligned)
#define XSTR  72     // x_lds row stride in bf16 (144 B)

typedef __attribute__((ext_vector_type(8))) short bf8;     // MFMA A/B frag
typedef __attribute__((ext_vector_type(4))) float f32x4;   // MFMA C/D frag
typedef __attribute__((ext_vector_type(2))) unsigned u32x2;

static __device__ __forceinline__ short f2bf(float f) {    // fp32 -> bf16 RNE
    unsigned u = __builtin_bit_cast(unsigned, f);
    u = (u + 0x7FFFu + ((u >> 16) & 1u)) >> 16;
    return (short)u;
}
static __device__ __forceinline__ float bf2f(short s) {
    unsigned u = ((unsigned)(unsigned short)s) << 16;
    return __builtin_bit_cast(float, u);
}
// pack two f32 -> one u32 of 2x bf16 (lo=a, hi=b), RNE, pure C.
// R9 lesson (matches learn_hip m240): inline-asm v_cvt_pk_bf16_f32 on this
// path cost -39% wall (asm serializes the epilogue); plain bit-ops are
// schedulable and bit-identical to f2bf pairs.
static __device__ __forceinline__ unsigned pk2bf(float a, float b) {
    unsigned ua = __builtin_bit_cast(unsigned, a);
    unsigned ub = __builtin_bit_cast(unsigned, b);
    ua = (ua + 0x7FFFu + ((ua >> 16) & 1u)) >> 16;
    ub = (ub + 0x7FFFu + ((ub >> 16) & 1u)) & 0xFFFF0000u;
    return ua | ub;
}

// 64 blocks x 256 threads, block owns 16 batch rows for the whole sequence.
// D[j][m] = MFMA(A=W-frags, B=h-frags): lane's 4 C-regs are 4 ADJACENT
// j-columns of one h_lds row -> tanh outputs pack to u32 pairs and store as
// ONE ds_write_b64 per tile; x staging is 16 lanes/row x 4 contiguous elems.
// R10 = R9 with the inline-asm cvt_pk replaced by pure-C packing (single
// variable vs R9; tests whether the asm caused the 607->1000us regression).
__global__ __launch_bounds__(256) void rnn_mfma_kernel(
    const float* __restrict__ X,     // [SEQ][BATCH][IN_F]
    const float* __restrict__ W_ih,  // [H_F][IN_F]
    const float* __restrict__ b_ih,  // [H_F]
    const float* __restrict__ W_hh,  // [H_F][H_F]
    const float* __restrict__ b_hh,  // [H_F]
    const float* __restrict__ W_ho,  // [OUT_F][H_F]
    const float* __restrict__ b_ho,  // [OUT_F]
    float* __restrict__ out)         // [BATCH][OUT_F] ++ [BATCH][H_F]
{
    const int tid  = threadIdx.x;
    const int lane = tid & 63;
    const int wv   = tid >> 6;
    const int n16  = lane & 15;
    const int quad = lane >> 4;
    const int b0   = blockIdx.x * MROWS;

    __shared__ short h_lds[2][MROWS][HSTR];
    __shared__ short x_lds[2][MROWS][XSTR];
    __shared__ float logits_lds[MROWS][OUT_F];
    __shared__ float red_lds[MROWS][2];

    const int j0 = wv * 32 + n16;
    const int j1 = j0 + 16;

    // ---- W_hh frags (bf16) in registers: lane holds W[j][k=quad*8+i]. ----
    const float* wp0 = W_hh + j0 * H_F + quad * 8;
    const float* wp1 = W_hh + j1 * H_F + quad * 8;
#define LDW8(P) ({ \
        f32x4 p_ = *(const f32x4*)(P); \
        f32x4 q_ = *(const f32x4*)((P) + 4); \
        bf8 f_; \
        f_[0]=f2bf(p_[0]); f_[1]=f2bf(p_[1]); f_[2]=f2bf(p_[2]); f_[3]=f2bf(p_[3]); \
        f_[4]=f2bf(q_[0]); f_[5]=f2bf(q_[1]); f_[6]=f2bf(q_[2]); f_[7]=f2bf(q_[3]); \
        f_; })
    bf8 wh00 = LDW8(wp0 +  0), wh01 = LDW8(wp0 + 32), wh02 = LDW8(wp0 + 64), wh03 = LDW8(wp0 + 96);
    bf8 wh10 = LDW8(wp1 +  0), wh11 = LDW8(wp1 + 32), wh12 = LDW8(wp1 + 64), wh13 = LDW8(wp1 + 96);

    // ---- W_ih frags (K 57->64 zero-pad) ----
#define LDWI(J, KS) ({ \
        bf8 f_; \
        _Pragma("unroll") \
        for (int i_ = 0; i_ < 8; ++i_) { \
            int k_ = (KS) * 32 + quad * 8 + i_; \
            f_[i_] = (k_ < IN_F) ? f2bf(W_ih[(J) * IN_F + k_]) : (short)0; \
        } f_; })
    bf8 wi00 = LDWI(j0, 0), wi01 = LDWI(j0, 1), wi10 = LDWI(j1, 0), wi11 = LDWI(j1, 1);

    // ---- bias vectors: D[j][m] rows j = wv*32 + 16*tile + 4*quad + r ----
    const int jq0 = wv * 32 + 4 * quad;
    f32x4 biasA, biasB;
    {
        f32x4 a0 = *(const f32x4*)(b_ih + jq0);
        f32x4 a1 = *(const f32x4*)(b_hh + jq0);
        biasA = a0 + a1;
        f32x4 b0v = *(const f32x4*)(b_ih + jq0 + 16);
        f32x4 b1v = *(const f32x4*)(b_hh + jq0 + 16);
        biasB = b0v + b1v;
    }

    // ---- x staging: 16 lanes per batch row, lane s handles k = 4s..4s+3 ----
    const int xs  = tid & 15;       // segment within row
    const int xm_ = tid >> 4;       // batch row 0..15
    const int xk0 = xs * 4;
    const bool xv = (xs < 14);      // vector lanes: k 0..55
    const bool x1 = (xs == 14);     // scalar lane:  k 56
    const size_t tstride = (size_t)BATCH * IN_F;
    const float* xb4 = X + (size_t)(b0 + xm_) * IN_F + xk0;
    const float* xb1 = X + (size_t)(b0 + xm_) * IN_F + 56;

#define XSTAGE(NB, V, S) do { \
        if (xv) { \
            u32x2 w_; \
            w_[0] = pk2bf((V)[0], (V)[1]); \
            w_[1] = pk2bf((V)[2], (V)[3]); \
            *(u32x2*)&x_lds[NB][xm_][xk0] = w_; \
        } else if (x1) { \
            x_lds[NB][xm_][56] = f2bf(S); \
        } } while (0)

    // ---- init: h0 = 0, zero x pads, stage x_0, prefetch x_1, x_2 ----
    for (int i = tid; i < MROWS * HSTR; i += 256) (&h_lds[0][0][0])[i] = 0;
    for (int i = tid; i < 2 * MROWS * XSTR; i += 256) (&x_lds[0][0][0])[i] = 0;
    f32x4 xq0 = {0,0,0,0}, xq1 = {0,0,0,0};
    float xq0s = 0.f, xq1s = 0.f;
    if (xv) {
        f32x4 v = *(const f32x4*)xb4;
        XSTAGE(0, v, 0.f);
        xq1 = *(const f32x4*)(xb4 + 1 * tstride);   // x_1 (written at T=0)
        xq0 = *(const f32x4*)(xb4 + 2 * tstride);   // x_2 (written at T=1)
    } else if (x1) {
        x_lds[0][xm_][56] = f2bf(*xb1);
        xq1s = xb1[1 * tstride];
        xq0s = xb1[2 * tstride];
    }
    __syncthreads();

    // Raw barrier: LDS visibility needs only lgkmcnt(0); do NOT drain vmcnt
    // (keeps x prefetch in flight; proven-safe in R6).
#define STEP_BARRIER() do { \
        asm volatile("s_waitcnt lgkmcnt(0)" ::: "memory"); \
        __builtin_amdgcn_s_barrier(); \
    } while (0)

    // tanh(z) = 1 - 2/(e^{2z}+1); one-sided clamp (z << 0 -> exp -> 0 -> -1)
#define TH(Z) ({ \
        float z_ = fminf((Z), 9.f); \
        float e_ = __expf(2.f * z_); \
        fmaf(-2.f, __builtin_amdgcn_rcpf(e_ + 1.f), 1.f); })

#define MFMA __builtin_amdgcn_mfma_f32_16x16x32_bf16
#define STEP(CB, NB, T, XS, XSS) do { \
        /* B-frags (h rows / x rows) */ \
        const short* hc = &h_lds[CB][0][0] + n16 * HSTR + quad * 8; \
        const short* xc = &x_lds[CB][0][0] + n16 * XSTR + quad * 8; \
        bf8 bh0 = *(const bf8*)(hc +  0); \
        bf8 bh1 = *(const bf8*)(hc + 32); \
        bf8 bh2 = *(const bf8*)(hc + 64); \
        bf8 bh3 = *(const bf8*)(hc + 96); \
        bf8 bx0 = *(const bf8*)(xc +  0); \
        bf8 bx1 = *(const bf8*)(xc + 32); \
        /* stage x_{T+1} (loaded 2 steps ago) into NB now */ \
        if ((T) + 1 < SEQ) XSTAGE(NB, XS, XSS); \
        /* issue load of x_{T+3} into the same parity slot */ \
        if ((T) + 3 < SEQ) { \
            if (xv)      XS  = *(const f32x4*)(xb4 + (size_t)((T) + 3) * tstride); \
            else if (x1) XSS = xb1[(size_t)((T) + 3) * tstride]; \
        } \
        /* 12 MFMAs, 4 chains of depth 3; A = W-frags, B = h/x-frags */ \
        f32x4 c0a = biasA, c0b = {0.f, 0.f, 0.f, 0.f}; \
        f32x4 c1a = biasB, c1b = {0.f, 0.f, 0.f, 0.f}; \
        c0a = MFMA(wh00, bh0, c0a, 0, 0, 0); \
        c1a = MFMA(wh10, bh0, c1a, 0, 0, 0); \
        c0b = MFMA(wh01, bh1, c0b, 0, 0, 0); \
        c1b = MFMA(wh11, bh1, c1b, 0, 0, 0); \
        c0a = MFMA(wh02, bh2, c0a, 0, 0, 0); \
        c1a = MFMA(wh12, bh2, c1a, 0, 0, 0); \
        c0b = MFMA(wh03, bh3, c0b, 0, 0, 0); \
        c1b = MFMA(wh13, bh3, c1b, 0, 0, 0); \
        c0a = MFMA(wi00, bx0, c0a, 0, 0, 0); \
        c1a = MFMA(wi10, bx0, c1a, 0, 0, 0); \
        c0b = MFMA(wi01, bx1, c0b, 0, 0, 0); \
        c1b = MFMA(wi11, bx1, c1b, 0, 0, 0); \
        /* D[j][m]: lane (quad,n16) holds j = jq0 + {0..3} (+16), m = n16.  */ \
        /* tanh -> C-pack pairs -> one b64 store per tile into row-major h. */ \
        { \
            float t0_ = TH(c0a[0] + c0b[0]); \
            float t1_ = TH(c0a[1] + c0b[1]); \
            float t2_ = TH(c0a[2] + c0b[2]); \
            float t3_ = TH(c0a[3] + c0b[3]); \
            u32x2 w_; \
            w_[0] = pk2bf(t0_, t1_); \
            w_[1] = pk2bf(t2_, t3_); \
            *(u32x2*)&h_lds[NB][n16][jq0] = w_; \
        } \
        { \
            float t0_ = TH(c1a[0] + c1b[0]); \
            float t1_ = TH(c1a[1] + c1b[1]); \
            float t2_ = TH(c1a[2] + c1b[2]); \
            float t3_ = TH(c1a[3] + c1b[3]); \
            u32x2 w_; \
            w_[0] = pk2bf(t0_, t1_); \
            w_[1] = pk2bf(t2_, t3_); \
            *(u32x2*)&h_lds[NB][n16][jq0 + 16] = w_; \
        } \
        STEP_BARRIER(); \
    } while (0)

    for (int t = 0; t < SEQ; t += 2) {
        STEP(0, 1, t,     xq1, xq1s);
        STEP(1, 0, t + 1, xq0, xq0s);
    }
#undef STEP
#undef MFMA

    // ---- final h (buf0) -> hT ----
    float* hT = out + (size_t)BATCH * OUT_F;
    #pragma unroll
    for (int r = 0; r < (MROWS * H_F) / 256; ++r) {
        int idx = tid + r * 256;
        int m = idx >> 7, k = idx & 127;
        hT[(size_t)(b0 + m) * H_F + k] = bf2f(h_lds[0][m][k]);
    }

    // ---- logits [16][18] ----
    for (int idx = tid; idx < MROWS * OUT_F; idx += 256) {
        int m = idx / OUT_F, o = idx - m * OUT_F;
        float acc = b_ho[o];
        for (int k = 0; k < H_F; ++k)
            acc = fmaf(bf2f(h_lds[0][m][k]), W_ho[o * H_F + k], acc);
        logits_lds[m][o] = acc;
    }
    __syncthreads();

    if (tid < MROWS) {
        float mx = -1e30f;
        #pragma unroll
        for (int o = 0; o < OUT_F; ++o) mx = fmaxf(mx, logits_lds[tid][o]);
        float s = 0.f;
        #pragma unroll
        for (int o = 0; o < OUT_F; ++o) s += expf(logits_lds[tid][o] - mx);
        red_lds[tid][0] = mx;
        red_lds[tid][1] = logf(s);
    }
    __syncthreads();

    for (int idx = tid; idx < MROWS * OUT_F; idx += 256) {
        int m = idx / OUT_F, o = idx - m * OUT_F;
        out[(size_t)(b0 + m) * OUT_F + o] =
            logits_lds[m][o] - red_lds[m][0] - red_lds[m][1];
    }
}

extern "C" void kernel_launch(void* const* d_in, const int* in_sizes, int n_in,
                              void* d_out, int out_size, void* d_ws, size_t ws_size,
                              hipStream_t stream) {
    const float* X    = (const float*)d_in[0];
    const float* W_ih = (const float*)d_in[1];
    const float* b_ih = (const float*)d_in[2];
    const float* W_hh = (const float*)d_in[3];
    const float* b_hh = (const float*)d_in[4];
    const float* W_ho = (const float*)d_in[5];
    const float* b_ho = (const float*)d_in[6];
    float* out = (float*)d_out;

    rnn_mfma_kernel<<<dim3(BATCH / MROWS), dim3(256), 0, stream>>>(
        X, W_ih, b_ih, W_hh, b_hh, W_ho, b_ho, out);
}

// Round 7
// 809.182 us; speedup vs baseline: 1.5936x; 1.5936x over previous
//
#include <hip/hip_runtime.h>
#include <math.h>

#define SEQ   1024
#define BATCH 1024
#define IN_F  57
#define H_F   128
#define OUT_F 18
#define MROWS 16     // batch rows per block
#define HSTR  136    // h_lds row stride in bf16 (272 B, 16B-aligned)
#define XSTR  72     // x_lds row stride in bf16 (144 B)
#define NT    512    // 8 waves: 2 waves/SIMD -> latency hiding (R11)

typedef __attribute__((ext_vector_type(8))) short bf8;     // MFMA A/B frag
typedef __attribute__((ext_vector_type(4))) float f32x4;   // MFMA C/D frag

static __device__ __forceinline__ short f2bf(float f) {    // fp32 -> bf16 RNE
    unsigned u = __builtin_bit_cast(unsigned, f);
    u = (u + 0x7FFFu + ((u >> 16) & 1u)) >> 16;
    return (short)u;
}
static __device__ __forceinline__ float bf2f(short s) {
    unsigned u = ((unsigned)(unsigned short)s) << 16;
    return __builtin_bit_cast(float, u);
}

// 64 blocks, block owns 16 batch rows for the whole sequence.
// R11 model (from R6/R9/R10 falsifications): busy counters are constant
// (~20us MFMA + ~60us VALU) across 607..1055us walls -> ~85% of the step is
// EXPOSED LATENCY, because 256 threads = 1 wave/SIMD = zero TLP. Fix: 512
// threads = 8 waves = 2/SIMD; each wave owns ONE 16-col j-tile (6 MFMAs,
// 4 tanh/writes) instead of two. Per-wave serial chain halves and the two
// co-resident waves hide each other's ds_read/MFMA/exp latencies.
// Everything else is byte-for-byte the proven 607us R6 kernel: same staging
// map, same non-vmcnt-draining barrier, same tanh, same write pattern.
__global__ __launch_bounds__(NT) void rnn_mfma_kernel(
    const float* __restrict__ X,     // [SEQ][BATCH][IN_F]
    const float* __restrict__ W_ih,  // [H_F][IN_F]
    const float* __restrict__ b_ih,  // [H_F]
    const float* __restrict__ W_hh,  // [H_F][H_F]
    const float* __restrict__ b_hh,  // [H_F]
    const float* __restrict__ W_ho,  // [OUT_F][H_F]
    const float* __restrict__ b_ho,  // [OUT_F]
    float* __restrict__ out)         // [BATCH][OUT_F] ++ [BATCH][H_F]
{
    const int tid  = threadIdx.x;
    const int lane = tid & 63;
    const int wv   = tid >> 6;       // 0..7
    const int n16  = lane & 15;
    const int quad = lane >> 4;
    const int b0   = blockIdx.x * MROWS;

    __shared__ short h_lds[2][MROWS][HSTR];
    __shared__ short x_lds[2][MROWS][XSTR];
    __shared__ float logits_lds[MROWS][OUT_F];
    __shared__ float red_lds[MROWS][2];

    // wave wv owns output cols [16wv, 16wv+16) as ONE 16x16x32 tile
    const int j0 = wv * 16 + n16;

    // ---- W_hh B-frags (bf16) in registers ----
    const float* wp0 = W_hh + j0 * H_F + quad * 8;
#define LDW8(P) ({ \
        f32x4 p_ = *(const f32x4*)(P); \
        f32x4 q_ = *(const f32x4*)((P) + 4); \
        bf8 f_; \
        f_[0]=f2bf(p_[0]); f_[1]=f2bf(p_[1]); f_[2]=f2bf(p_[2]); f_[3]=f2bf(p_[3]); \
        f_[4]=f2bf(q_[0]); f_[5]=f2bf(q_[1]); f_[6]=f2bf(q_[2]); f_[7]=f2bf(q_[3]); \
        f_; })
    bf8 wh0 = LDW8(wp0 +  0), wh1 = LDW8(wp0 + 32), wh2 = LDW8(wp0 + 64), wh3 = LDW8(wp0 + 96);

    // ---- W_ih B-frags (K 57->64 zero-pad) ----
#define LDWI(J, KS) ({ \
        bf8 f_; \
        _Pragma("unroll") \
        for (int i_ = 0; i_ < 8; ++i_) { \
            int k_ = (KS) * 32 + quad * 8 + i_; \
            f_[i_] = (k_ < IN_F) ? f2bf(W_ih[(J) * IN_F + k_]) : (short)0; \
        } f_; })
    bf8 wi0 = LDWI(j0, 0), wi1 = LDWI(j0, 1);

    const float bias0 = b_ih[j0] + b_hh[j0];

    // ---- x staging constants: 912 floats/step = 228 f32x4 lanes ----
    const bool  xlane = (tid < 228);     // waves 0-2 uniform-true, wave 3
                                         // divergent, waves 4-7 uniform-false
    const size_t tstride = (size_t)BATCH * IN_F;
    const float* xbase = X + (size_t)b0 * IN_F + tid * 4;
    int xm[4], xk[4];
    #pragma unroll
    for (int e = 0; e < 4; ++e) {
        int idx = tid * 4 + e;
        xm[e] = (int)((unsigned)idx / 57u);
        xk[e] = idx - xm[e] * 57;
    }

    // ---- init: h0 = 0, zero x pads, stage x_0, prefetch x_1, x_2 ----
    for (int i = tid; i < MROWS * HSTR; i += NT) (&h_lds[0][0][0])[i] = 0;
    for (int i = tid; i < 2 * MROWS * XSTR; i += NT) (&x_lds[0][0][0])[i] = 0;
    f32x4 xq0 = {0,0,0,0}, xq1 = {0,0,0,0};
    if (xlane) {
        f32x4 v = *(const f32x4*)(xbase);
        #pragma unroll
        for (int e = 0; e < 4; ++e) x_lds[0][xm[e]][xk[e]] = f2bf(v[e]);
        xq1 = *(const f32x4*)(xbase + 1 * tstride);   // x_1  (written at T=0)
        xq0 = *(const f32x4*)(xbase + 2 * tstride);   // x_2  (written at T=1)
    }
    __syncthreads();

    // Raw barrier: LDS visibility needs only lgkmcnt(0); do NOT drain vmcnt
    // (keeps x prefetch in flight; proven perf-neutral-safe in R6).
#define STEP_BARRIER() do { \
        asm volatile("s_waitcnt lgkmcnt(0)" ::: "memory"); \
        __builtin_amdgcn_s_barrier(); \
    } while (0)

#define MFMA __builtin_amdgcn_mfma_f32_16x16x32_bf16
#define STEP(CB, NB, T, XS) do { \
        /* A-frags for this step (h rows m=n16, k=quad*8+i) */ \
        const short* hc = &h_lds[CB][0][0] + n16 * HSTR + quad * 8; \
        const short* xc = &x_lds[CB][0][0] + n16 * XSTR + quad * 8; \
        bf8 ah0 = *(const bf8*)(hc +  0); \
        bf8 ah1 = *(const bf8*)(hc + 32); \
        bf8 ah2 = *(const bf8*)(hc + 64); \
        bf8 ah3 = *(const bf8*)(hc + 96); \
        bf8 ax0 = *(const bf8*)(xc +  0); \
        bf8 ax1 = *(const bf8*)(xc + 32); \
        /* stage x_{T+1} (loaded 2 steps ago -> no vmcnt stall) into NB now */ \
        if (((T) + 1 < SEQ) && xlane) { \
            _Pragma("unroll") \
            for (int e = 0; e < 4; ++e) x_lds[NB][xm[e]][xk[e]] = f2bf(XS[e]); \
        } \
        /* issue load of x_{T+3} into the same parity slot */ \
        if (((T) + 3 < SEQ) && xlane) \
            XS = *(const f32x4*)(xbase + (size_t)((T) + 3) * tstride); \
        /* 6 MFMAs, 2 chains of depth 3 */ \
        f32x4 ca = {bias0, bias0, bias0, bias0}, cb = {0.f, 0.f, 0.f, 0.f}; \
        ca = MFMA(ah0, wh0, ca, 0, 0, 0); \
        cb = MFMA(ah1, wh1, cb, 0, 0, 0); \
        ca = MFMA(ah2, wh2, ca, 0, 0, 0); \
        cb = MFMA(ah3, wh3, cb, 0, 0, 0); \
        ca = MFMA(ax0, wi0, ca, 0, 0, 0); \
        cb = MFMA(ax1, wi1, cb, 0, 0, 0); \
        short* hn = &h_lds[NB][0][0]; \
        _Pragma("unroll") \
        for (int r = 0; r < 4; ++r) { \
            int m = quad * 4 + r; \
            float z = fminf(fmaxf(ca[r] + cb[r], -9.f), 9.f); \
            float e = __expf(2.f * z); \
            hn[m * HSTR + j0] = f2bf((e - 1.f) * __builtin_amdgcn_rcpf(e + 1.f)); \
        } \
        STEP_BARRIER(); \
    } while (0)

    for (int t = 0; t < SEQ; t += 2) {
        STEP(0, 1, t,     xq1);
        STEP(1, 0, t + 1, xq0);
    }
#undef STEP
#undef MFMA

    // ---- final h (buf0) -> hT ----
    float* hT = out + (size_t)BATCH * OUT_F;
    #pragma unroll
    for (int r = 0; r < (MROWS * H_F) / NT; ++r) {
        int idx = tid + r * NT;
        int m = idx >> 7, k = idx & 127;
        hT[(size_t)(b0 + m) * H_F + k] = bf2f(h_lds[0][m][k]);
    }

    // ---- logits [16][18] ----
    for (int idx = tid; idx < MROWS * OUT_F; idx += NT) {
        int m = idx / OUT_F, o = idx - m * OUT_F;
        float acc = b_ho[o];
        for (int k = 0; k < H_F; ++k)
            acc = fmaf(bf2f(h_lds[0][m][k]), W_ho[o * H_F + k], acc);
        logits_lds[m][o] = acc;
    }
    __syncthreads();

    if (tid < MROWS) {
        float mx = -1e30f;
        #pragma unroll
        for (int o = 0; o < OUT_F; ++o) mx = fmaxf(mx, logits_lds[tid][o]);
        float s = 0.f;
        #pragma unroll
        for (int o = 0; o < OUT_F; ++o) s += expf(logits_lds[tid][o] - mx);
        red_lds[tid][0] = mx;
        red_lds[tid][1] = logf(s);
    }
    __syncthreads();

    for (int idx = tid; idx < MROWS * OUT_F; idx += NT) {
        int m = idx / OUT_F, o = idx - m * OUT_F;
        out[(size_t)(b0 + m) * OUT_F + o] =
            logits_lds[m][o] - red_lds[m][0] - red_lds[m][1];
    }
}

extern "C" void kernel_launch(void* const* d_in, const int* in_sizes, int n_in,
                              void* d_out, int out_size, void* d_ws, size_t ws_size,
                              hipStream_t stream) {
    const float* X    = (const float*)d_in[0];
    const float* W_ih = (const float*)d_in[1];
    const float* b_ih = (const float*)d_in[2];
    const float* W_hh = (const float*)d_in[3];
    const float* b_hh = (const float*)d_in[4];
    const float* W_ho = (const float*)d_in[5];
    const float* b_ho = (const float*)d_in[6];
    float* out = (float*)d_out;

    rnn_mfma_kernel<<<dim3(BATCH / MROWS), dim3(NT), 0, stream>>>(
        X, W_ih, b_ih, W_hh, b_hh, W_ho, b_ho, out);
}

// Round 9
// 806.839 us; speedup vs baseline: 1.5983x; 1.0029x over previous
//
#include <hip/hip_runtime.h>
#include <math.h>

#define SEQ   1024
#define BATCH 1024
#define IN_F  57
#define H_F   128
#define OUT_F 18
#define MROWS 16     // batch rows per block
#define HSTR  136    // h_lds row stride in bf16 (272 B; m*272 spreads banks)
#define XSTR  72     // x_lds row stride in bf16 (144 B)
#define XPSTR 28     // xp row stride in f32 (112 B: 16B-aligned, j%8 bank spread)
#define NT    512    // 8 waves: 4 h-waves + 4 x-waves (producer/consumer)

typedef __attribute__((ext_vector_type(8))) short bf8;     // MFMA A/B frag
typedef __attribute__((ext_vector_type(4))) float f32x4;   // MFMA C/D frag

static __device__ __forceinline__ short f2bf(float f) {    // fp32 -> bf16 RNE
    unsigned u = __builtin_bit_cast(unsigned, f);
    u = (u + 0x7FFFu + ((u >> 16) & 1u)) >> 16;
    return (short)u;
}
static __device__ __forceinline__ float bf2f(short s) {
    unsigned u = ((unsigned)(unsigned short)s) << 16;
    return __builtin_bit_cast(float, u);
}

// R12/R13: producer-consumer wave specialization.
// R11 post-mortem: 2 lockstep waves/SIMD only bought 6% — the step is LDS-
// service bound (48 redundant ds_read_b128/step/CU) with the x-pipeline on
// the critical path. The x-projection doesn't depend on the recurrence, so:
//   waves 0-3 (h-waves): h_{t+1} cols [32wv,32wv+32) = tanh(xp_t + h_t@W_hh^T)
//       - acc INIT from xp_lds (bias + x-proj precomputed last step)
//       - only 4 h-frag b128 reads + 2 xp b128 reads, 8 MFMAs (2-deep chains)
//   waves 4-7 (x-waves): during step t compute xp_{t+1}=bias+x_{t+1}@W_ih^T
//       into xp_lds[t+1 parity] (4 MFMAs), stage x_{t+2}, prefetch x_{t+4}
// One barrier per step covers both handoffs (h and xp). h-step body is R6's
// proven code minus the x-half; numerics differ only in f32 add order.
// (R13 = R12 resubmitted verbatim after container-level infra failure.)
__global__ __launch_bounds__(NT) void rnn_mfma_kernel(
    const float* __restrict__ X,     // [SEQ][BATCH][IN_F]
    const float* __restrict__ W_ih,  // [H_F][IN_F]
    const float* __restrict__ b_ih,  // [H_F]
    const float* __restrict__ W_hh,  // [H_F][H_F]
    const float* __restrict__ b_hh,  // [H_F]
    const float* __restrict__ W_ho,  // [OUT_F][H_F]
    const float* __restrict__ b_ho,  // [OUT_F]
    float* __restrict__ out)         // [BATCH][OUT_F] ++ [BATCH][H_F]
{
    const int tid  = threadIdx.x;
    const int lane = tid & 63;
    const int wv   = tid >> 6;       // 0..7
    const int n16  = lane & 15;
    const int quad = lane >> 4;
    const int b0   = blockIdx.x * MROWS;
    const bool hw  = (wv < 4);       // wave-uniform role split
    const int  wv2 = wv & 3;

    __shared__ short h_lds[2][MROWS][HSTR];
    __shared__ short x_lds[2][MROWS][XSTR];
    __shared__ float xp_lds[2][H_F][XPSTR];   // xp^T[j][m] (bias folded), f32
    __shared__ float logits_lds[MROWS][OUT_F];
    __shared__ float red_lds[MROWS][2];

    // both roles: two 16-col j-tiles
    const int jt0 = wv2 * 32 + n16;
    const int jt1 = jt0 + 16;

    // ---- B-frags in registers: h-waves hold W_hh (K=128: 4 frags/tile);
    //      x-waves hold W_ih (K=64 zero-padded: 2 frags/tile). ----
    bf8 f0 = {0,0,0,0,0,0,0,0}, f1 = f0, f2 = f0, f3 = f0;
    bf8 g0 = f0, g1 = f0, g2 = f0, g3 = f0;
    float biasx0 = 0.f, biasx1 = 0.f;

#define LDW8(P) ({ \
        f32x4 p_ = *(const f32x4*)(P); \
        f32x4 q_ = *(const f32x4*)((P) + 4); \
        bf8 r_; \
        r_[0]=f2bf(p_[0]); r_[1]=f2bf(p_[1]); r_[2]=f2bf(p_[2]); r_[3]=f2bf(p_[3]); \
        r_[4]=f2bf(q_[0]); r_[5]=f2bf(q_[1]); r_[6]=f2bf(q_[2]); r_[7]=f2bf(q_[3]); \
        r_; })
#define LDWI(J, KS) ({ \
        bf8 r_; \
        _Pragma("unroll") \
        for (int i_ = 0; i_ < 8; ++i_) { \
            int k_ = (KS) * 32 + quad * 8 + i_; \
            r_[i_] = (k_ < IN_F) ? f2bf(W_ih[(J) * IN_F + k_]) : (short)0; \
        } r_; })

    if (hw) {
        const float* wp0 = W_hh + jt0 * H_F + quad * 8;
        const float* wp1 = W_hh + jt1 * H_F + quad * 8;
        f0 = LDW8(wp0 +  0); f1 = LDW8(wp0 + 32); f2 = LDW8(wp0 + 64); f3 = LDW8(wp0 + 96);
        g0 = LDW8(wp1 +  0); g1 = LDW8(wp1 + 32); g2 = LDW8(wp1 + 64); g3 = LDW8(wp1 + 96);
    } else {
        f0 = LDWI(jt0, 0); f1 = LDWI(jt0, 1);
        g0 = LDWI(jt1, 0); g1 = LDWI(jt1, 1);
        biasx0 = b_ih[jt0] + b_hh[jt0];
        biasx1 = b_ih[jt1] + b_hh[jt1];
    }

    // ---- x staging constants (x-waves only): 912 floats = 228 f32x4 lanes ----
    const int  tid2  = hw ? 0 : (tid - 256);
    const bool xlane = (!hw) && (tid2 < 228);
    const size_t tstride = (size_t)BATCH * IN_F;
    const float* xbase = X + (size_t)b0 * IN_F + tid2 * 4;
    int xm[4], xk[4];
    #pragma unroll
    for (int e = 0; e < 4; ++e) {
        int idx = tid2 * 4 + e;
        xm[e] = (int)((unsigned)idx / 57u);
        xk[e] = idx - xm[e] * 57;
    }

    // ---- init: h0 = 0, zero x pads; stage x_0; prefetch x_1..x_3 ----
    for (int i = tid; i < MROWS * HSTR; i += NT) (&h_lds[0][0][0])[i] = 0;
    for (int i = tid; i < 2 * MROWS * XSTR; i += NT) (&x_lds[0][0][0])[i] = 0;
    f32x4 xr1 = {0,0,0,0}, xqA = {0,0,0,0}, xqB = {0,0,0,0};
    if (xlane) {
        f32x4 v = *(const f32x4*)xbase;                    // x_0
        #pragma unroll
        for (int e = 0; e < 4; ++e) x_lds[0][xm[e]][xk[e]] = f2bf(v[e]);
        xr1 = *(const f32x4*)(xbase + 1 * tstride);        // x_1 (staged ph.2)
        xqA = *(const f32x4*)(xbase + 2 * tstride);        // x_2 (staged t=0)
        xqB = *(const f32x4*)(xbase + 3 * tstride);        // x_3 (staged t=1)
    }
    __syncthreads();

    // Raw barrier: LDS visibility needs only lgkmcnt(0); do NOT drain vmcnt.
#define STEP_BARRIER() do { \
        asm volatile("s_waitcnt lgkmcnt(0)" ::: "memory"); \
        __builtin_amdgcn_s_barrier(); \
    } while (0)

#define MFMA __builtin_amdgcn_mfma_f32_16x16x32_bf16

    // x-wave: xp[j][m] = bias_j + sum_k x[m][k] W_ih[j][k], written transposed
    // so h-waves read their 4 acc-init values as one b128.
#define XPCOMPUTE(SRC, DST) do { \
        const short* xc_ = &x_lds[SRC][0][0] + n16 * XSTR + quad * 8; \
        bf8 ax0_ = *(const bf8*)(xc_ +  0); \
        bf8 ax1_ = *(const bf8*)(xc_ + 32); \
        f32x4 c0_ = {biasx0, biasx0, biasx0, biasx0}; \
        f32x4 c1_ = {biasx1, biasx1, biasx1, biasx1}; \
        c0_ = MFMA(ax0_, f0, c0_, 0, 0, 0); \
        c1_ = MFMA(ax0_, g0, c1_, 0, 0, 0); \
        c0_ = MFMA(ax1_, f1, c0_, 0, 0, 0); \
        c1_ = MFMA(ax1_, g1, c1_, 0, 0, 0); \
        *(f32x4*)&xp_lds[DST][jt0][quad * 4] = c0_; \
        *(f32x4*)&xp_lds[DST][jt1][quad * 4] = c1_; \
    } while (0)

    // ---- prologue phase 2: xp_0, stage x_1 ----
    if (!hw) {
        XPCOMPUTE(0, 0);
        if (xlane) {
            #pragma unroll
            for (int e = 0; e < 4; ++e) x_lds[1][xm[e]][xk[e]] = f2bf(xr1[e]);
        }
    }
    STEP_BARRIER();

    // h-wave step: read xp_t + h_t frags, 8 MFMAs (two 2-deep chains per
    // tile pair), tanh, write h_{t+1}. Verbatim R6 structure minus x-half.
#define HSTEP(P) do { \
        const short* hc = &h_lds[P][0][0] + n16 * HSTR + quad * 8; \
        f32x4 ca = *(const f32x4*)&xp_lds[P][jt0][quad * 4]; \
        f32x4 cb = *(const f32x4*)&xp_lds[P][jt1][quad * 4]; \
        bf8 ah0 = *(const bf8*)(hc +  0); \
        bf8 ah1 = *(const bf8*)(hc + 32); \
        bf8 ah2 = *(const bf8*)(hc + 64); \
        bf8 ah3 = *(const bf8*)(hc + 96); \
        f32x4 da = {0.f,0.f,0.f,0.f}, db = {0.f,0.f,0.f,0.f}; \
        ca = MFMA(ah0, f0, ca, 0, 0, 0); \
        cb = MFMA(ah0, g0, cb, 0, 0, 0); \
        da = MFMA(ah2, f2, da, 0, 0, 0); \
        db = MFMA(ah2, g2, db, 0, 0, 0); \
        ca = MFMA(ah1, f1, ca, 0, 0, 0); \
        cb = MFMA(ah1, g1, cb, 0, 0, 0); \
        da = MFMA(ah3, f3, da, 0, 0, 0); \
        db = MFMA(ah3, g3, db, 0, 0, 0); \
        short* hn = &h_lds[P ^ 1][0][0]; \
        _Pragma("unroll") \
        for (int r = 0; r < 4; ++r) { \
            int m = quad * 4 + r; \
            float z0 = fminf(fmaxf(ca[r] + da[r], -9.f), 9.f); \
            float e0 = __expf(2.f * z0); \
            hn[m * HSTR + jt0] = f2bf((e0 - 1.f) * __builtin_amdgcn_rcpf(e0 + 1.f)); \
            float z1 = fminf(fmaxf(cb[r] + db[r], -9.f), 9.f); \
            float e1 = __expf(2.f * z1); \
            hn[m * HSTR + jt1] = f2bf((e1 - 1.f) * __builtin_amdgcn_rcpf(e1 + 1.f)); \
        } \
    } while (0)

    // x-wave step t: xp_{t+1} from x_lds[P^1]; stage x_{t+2} into x_lds[P]
    // (x_t is dead there); prefetch x_{t+4}.
#define XSTEP(P, T, XS) do { \
        if ((T) + 1 < SEQ) { \
            XPCOMPUTE(P ^ 1, P ^ 1); \
            if (((T) + 2 < SEQ) && xlane) { \
                _Pragma("unroll") \
                for (int e = 0; e < 4; ++e) x_lds[P][xm[e]][xk[e]] = f2bf(XS[e]); \
            } \
            if (((T) + 4 < SEQ) && xlane) \
                XS = *(const f32x4*)(xbase + (size_t)((T) + 4) * tstride); \
        } \
    } while (0)

    for (int t = 0; t < SEQ; t += 2) {
        if (hw) HSTEP(0); else XSTEP(0, t, xqA);
        STEP_BARRIER();
        if (hw) HSTEP(1); else XSTEP(1, t + 1, xqB);
        STEP_BARRIER();
    }
#undef HSTEP
#undef XSTEP
#undef XPCOMPUTE
#undef MFMA

    // ---- final h (buf0) -> hT ----
    float* hT = out + (size_t)BATCH * OUT_F;
    #pragma unroll
    for (int r = 0; r < (MROWS * H_F) / NT; ++r) {
        int idx = tid + r * NT;
        int m = idx >> 7, k = idx & 127;
        hT[(size_t)(b0 + m) * H_F + k] = bf2f(h_lds[0][m][k]);
    }

    // ---- logits [16][18] ----
    for (int idx = tid; idx < MROWS * OUT_F; idx += NT) {
        int m = idx / OUT_F, o = idx - m * OUT_F;
        float acc = b_ho[o];
        for (int k = 0; k < H_F; ++k)
            acc = fmaf(bf2f(h_lds[0][m][k]), W_ho[o * H_F + k], acc);
        logits_lds[m][o] = acc;
    }
    __syncthreads();

    if (tid < MROWS) {
        float mx = -1e30f;
        #pragma unroll
        for (int o = 0; o < OUT_F; ++o) mx = fmaxf(mx, logits_lds[tid][o]);
        float s = 0.f;
        #pragma unroll
        for (int o = 0; o < OUT_F; ++o) s += expf(logits_lds[tid][o] - mx);
        red_lds[tid][0] = mx;
        red_lds[tid][1] = logf(s);
    }
    __syncthreads();

    for (int idx = tid; idx < MROWS * OUT_F; idx += NT) {
        int m = idx / OUT_F, o = idx - m * OUT_F;
        out[(size_t)(b0 + m) * OUT_F + o] =
            logits_lds[m][o] - red_lds[m][0] - red_lds[m][1];
    }
}

extern "C" void kernel_launch(void* const* d_in, const int* in_sizes, int n_in,
                              void* d_out, int out_size, void* d_ws, size_t ws_size,
                              hipStream_t stream) {
    const float* X    = (const float*)d_in[0];
    const float* W_ih = (const float*)d_in[1];
    const float* b_ih = (const float*)d_in[2];
    const float* W_hh = (const float*)d_in[3];
    const float* b_hh = (const float*)d_in[4];
    const float* W_ho = (const float*)d_in[5];
    const float* b_ho = (const float*)d_in[6];
    float* out = (float*)d_out;

    rnn_mfma_kernel<<<dim3(BATCH / MROWS), dim3(NT), 0, stream>>>(
        X, W_ih, b_ih, W_hh, b_hh, W_ho, b_ho, out);
}